// Round 8
// baseline (1424.147 us; speedup 1.0000x reference)
//
#include <hip/hip_runtime.h>
#include <hip/hip_bf16.h>

#define NN 80000
#define NE 1280000
#define NL 4
#define NG 256

__device__ __forceinline__ float wave_sum(float v) {
    for (int off = 32; off; off >>= 1) v += __shfl_xor(v, off, 64);
    return v;
}

// ---------------- CSR build ----------------
__global__ void k_count(const int* __restrict__ dst, int* __restrict__ cnt) {
    int e = blockIdx.x * 256 + threadIdx.x;
    if (e < NE) atomicAdd(&cnt[dst[e]], 1);
}

__global__ void k_scan1(const int* __restrict__ in, int* __restrict__ out,
                        int* __restrict__ bsum, int n) {
    __shared__ int ws[4];
    int i = blockIdx.x * 256 + threadIdx.x;
    int v = (i < n) ? in[i] : 0;
    int lane = threadIdx.x & 63, w = threadIdx.x >> 6;
    for (int off = 1; off < 64; off <<= 1) {
        int t = __shfl_up(v, off, 64);
        if (lane >= off) v += t;
    }
    if (lane == 63) ws[w] = v;
    __syncthreads();
    if (threadIdx.x == 0) {
        int acc = 0;
        for (int k = 0; k < 4; k++) { int t = ws[k]; ws[k] = acc; acc += t; }
    }
    __syncthreads();
    v += ws[w];
    if (i < n) out[i] = v;
    if (threadIdx.x == 255) bsum[blockIdx.x] = v;
}

__global__ void k_scan2(int* __restrict__ bsum, int nb) {
    __shared__ int ws[4];
    __shared__ int carry;
    if (threadIdx.x == 0) carry = 0;
    __syncthreads();
    for (int base = 0; base < nb; base += 256) {
        int i = base + threadIdx.x;
        int v = (i < nb) ? bsum[i] : 0;
        int lane = threadIdx.x & 63, w = threadIdx.x >> 6;
        for (int off = 1; off < 64; off <<= 1) {
            int t = __shfl_up(v, off, 64);
            if (lane >= off) v += t;
        }
        if (lane == 63) ws[w] = v;
        __syncthreads();
        if (threadIdx.x == 0) {
            int acc = carry;
            for (int k = 0; k < 4; k++) { int t = ws[k]; ws[k] = acc; acc += t; }
            carry = acc;
        }
        __syncthreads();
        v += ws[w];
        if (i < nb) bsum[i] = v;
        __syncthreads();
    }
}

__global__ void k_scan3(int* __restrict__ rowptr, const int* __restrict__ bsum, int n) {
    int i = blockIdx.x * 256 + threadIdx.x;
    if (i < n) {
        int off = (blockIdx.x > 0) ? bsum[blockIdx.x - 1] : 0;
        rowptr[1 + i] += off;
    }
    if (i == 0 && blockIdx.x == 0) rowptr[0] = 0;
}

// pack (src<<10)|combo into one int (src<2^17, combo<1000)
__global__ void k_fill(const int* __restrict__ src, const int* __restrict__ dst,
                       const int* __restrict__ eattr, const int* __restrict__ rowptr,
                       int* __restrict__ wofs, int* __restrict__ csr32) {
    int e = blockIdx.x * 256 + threadIdx.x;
    if (e >= NE) return;
    int d = dst[e];
    int pos = rowptr[d] + atomicAdd(&wofs[d], 1);
    int a0 = eattr[e * 3], a1 = eattr[e * 3 + 1], a2 = eattr[e * 3 + 2];
    csr32[pos] = (src[e] << 10) | (a0 + a1 * 10 + a2 * 100);
}

// ---------------- encoders / weight packing ----------------
__global__ void k_comb(const float* __restrict__ bond_emb, float* __restrict__ comb) {
    int wid = (blockIdx.x * 256 + threadIdx.x) >> 6;
    int lane = threadIdx.x & 63;
    if (wid >= 1000) return;
    int a0 = wid % 10, a1 = (wid / 10) % 10, a2 = wid / 100;
    comb[wid * 64 + lane] = bond_emb[a0 * 64 + lane] +
                            bond_emb[(10 + a1) * 64 + lane] +
                            bond_emb[(20 + a2) * 64 + lane];
}

__global__ void k_atom(const int* __restrict__ x, const float* __restrict__ atom_emb,
                       float* __restrict__ xn) {
    int wid = (blockIdx.x * 256 + threadIdx.x) >> 6;
    int lane = threadIdx.x & 63;
    if (wid >= NN) return;
    float acc = 0.f;
#pragma unroll
    for (int f = 0; f < 9; f++) {
        int idx = x[wid * 9 + f] + f * 100;
        acc += atom_emb[idx * 64 + lane];
    }
    xn[wid * 64 + lane] = acc;
}

// W1p[l][k][lane] = {W1[l][k][lane], W1[l][k][64+lane]}
// W2p[l][j][lane] = {W2[l][j][lane], W2[l][64+j][lane]}
__global__ void k_packw(const float* __restrict__ W1, const float* __restrict__ W2,
                        float2* __restrict__ W1p, float2* __restrict__ W2p) {
    int i = blockIdx.x * 256 + threadIdx.x;
    if (i >= NL * 64 * 64) return;
    int lane = i & 63, k = (i >> 6) & 63, l = i >> 12;
    W1p[i] = make_float2(W1[(l * 64 + k) * 128 + lane],
                         W1[(l * 64 + k) * 128 + 64 + lane]);
    W2p[i] = make_float2(W2[(l * 128 + k) * 64 + lane],
                         W2[(l * 128 + 64 + k) * 64 + lane]);
}

// ---------------- fused conv: edge-agg + MLP + residual + next-layer prenorm ----------------
// NOTE: hh_out must NOT alias hin (same-dispatch gather race) — caller ping-pongs buffers.
__global__ __launch_bounds__(256) void k_conv(
    const float* __restrict__ hin, const int* __restrict__ rowptr,
    const int* __restrict__ csr32, const float* __restrict__ comb,
    const float* __restrict__ t, int l,
    const float2* __restrict__ W1p, const float* __restrict__ b1,
    const float* __restrict__ g1, const float* __restrict__ bb1,
    const float2* __restrict__ W2p, const float* __restrict__ b2,
    float* __restrict__ cur, int residual,
    float* __restrict__ hh, const float* __restrict__ ng, const float* __restrict__ nb) {
    int wid = (blockIdx.x * 256 + threadIdx.x) >> 6;
    int lane = threadIdx.x & 63;
    if (wid >= NN) return;
    float tl = t[l];
    long oi = (long)wid * 64 + lane;
    float hroot = hin[oi];
    int rs = rowptr[wid], re = rowptr[wid + 1];

    // ---- branch-free aggregation (msg bounded post-LN-ReLU; exp(msg*t) fp32-safe) ----
    float den0 = 0.f, num0 = 0.f, den1 = 0.f, num1 = 0.f;
    for (int base = rs; base < re; base += 64) {
        int nbt = min(64, re - base);
        int ev = (base + lane < re) ? csr32[base + lane] : 0;
        int q = 0;
        for (; q + 3 < nbt; q += 4) {
            int v0 = __shfl(ev, q, 64),     v1 = __shfl(ev, q + 1, 64);
            int v2 = __shfl(ev, q + 2, 64), v3 = __shfl(ev, q + 3, 64);
            float h0 = hin[(long)(v0 >> 10) * 64 + lane];
            float c0 = comb[(v0 & 1023) * 64 + lane];
            float h1 = hin[(long)(v1 >> 10) * 64 + lane];
            float c1 = comb[(v1 & 1023) * 64 + lane];
            float h2 = hin[(long)(v2 >> 10) * 64 + lane];
            float c2 = comb[(v2 & 1023) * 64 + lane];
            float h3 = hin[(long)(v3 >> 10) * 64 + lane];
            float c3 = comb[(v3 & 1023) * 64 + lane];
            float m0 = fmaxf(h0 + c0, 0.f) + 1e-7f;
            float m1 = fmaxf(h1 + c1, 0.f) + 1e-7f;
            float m2 = fmaxf(h2 + c2, 0.f) + 1e-7f;
            float m3 = fmaxf(h3 + c3, 0.f) + 1e-7f;
            float e0 = __expf(m0 * tl), e1 = __expf(m1 * tl);
            float e2 = __expf(m2 * tl), e3 = __expf(m3 * tl);
            den0 += e0; num0 = fmaf(e0, m0, num0);
            den1 += e1; num1 = fmaf(e1, m1, num1);
            den0 += e2; num0 = fmaf(e2, m2, num0);
            den1 += e3; num1 = fmaf(e3, m3, num1);
        }
        for (; q < nbt; ++q) {
            int v0 = __shfl(ev, q, 64);
            float h0 = hin[(long)(v0 >> 10) * 64 + lane];
            float c0 = comb[(v0 & 1023) * 64 + lane];
            float m0 = fmaxf(h0 + c0, 0.f) + 1e-7f;
            float e0 = __expf(m0 * tl);
            den0 += e0; num0 = fmaf(e0, m0, num0);
        }
    }
    float den = den0 + den1, num = num0 + num1;
    float o = num / (den + 1e-16f) + hroot;
    float curold = residual ? cur[oi] : 0.f;

    // ---- MLP 64 -> 128 -> LN -> ReLU -> 64 (packed float2 weights) ----
    const float2* W1l = W1p + l * 4096;
    const float2* W2l = W2p + l * 4096;
    float a0 = b1[l * 128 + lane];
    float a1 = b1[l * 128 + 64 + lane];
#pragma unroll 8
    for (int k = 0; k < 64; ++k) {
        float ok = __shfl(o, k, 64);
        float2 w = W1l[k * 64 + lane];
        a0 = fmaf(ok, w.x, a0);
        a1 = fmaf(ok, w.y, a1);
    }
    float mu = wave_sum(a0 + a1) * (1.f / 128.f);
    float d0 = a0 - mu, d1 = a1 - mu;
    float var = wave_sum(d0 * d0 + d1 * d1) * (1.f / 128.f);
    float r = rsqrtf(var + 1e-5f);
    float m0 = fmaxf(d0 * r * g1[l * 128 + lane] + bb1[l * 128 + lane], 0.f);
    float m1 = fmaxf(d1 * r * g1[l * 128 + 64 + lane] + bb1[l * 128 + 64 + lane], 0.f);
    float acc = b2[l * 64 + lane];
#pragma unroll 8
    for (int j = 0; j < 64; ++j) {
        float v0 = __shfl(m0, j, 64);
        float v1 = __shfl(m1, j, 64);
        float2 w = W2l[j * 64 + lane];
        acc = fmaf(v0, w.x, acc);
        acc = fmaf(v1, w.y, acc);
    }
    float curv = curold + acc;
    cur[oi] = curv;

    // ---- fused next-layer prenorm: hh = relu(LN(curv; ng, nb)) ----
    if (hh) {
        float mu2 = wave_sum(curv) * (1.f / 64.f);
        float dd = curv - mu2;
        float var2 = wave_sum(dd * dd) * (1.f / 64.f);
        hh[oi] = fmaxf(dd * rsqrtf(var2 + 1e-5f) * ng[lane] + nb[lane], 0.f);
    }
}

// ---------------- pooling (atomic-free, batch sorted) ----------------
__global__ void k_bounds(const int* __restrict__ batch, int* __restrict__ gstart) {
    int i = blockIdx.x * 256 + threadIdx.x;
    if (i >= NN) return;
    int b = batch[i];
    if (i == 0) {
        for (int g = 0; g <= b; ++g) gstart[g] = 0;
    } else {
        int pb = batch[i - 1];
        for (int g = pb + 1; g <= b; ++g) gstart[g] = i;
    }
    if (i == NN - 1) {
        for (int g = b + 1; g <= NG; ++g) gstart[g] = NN;
    }
}

__global__ __launch_bounds__(1024) void k_pool2(
    const float* __restrict__ cur, const int* __restrict__ gstart,
    const float* __restrict__ g, const float* __restrict__ b,
    float* __restrict__ out) {
    int gi = blockIdx.x;
    int lane = threadIdx.x & 63, w = threadIdx.x >> 6;
    int s = gstart[gi], e = gstart[gi + 1];
    float gg = g[lane], bb = b[lane];
    float acc = 0.f;
    for (int n = s + w; n < e; n += 16) {
        float v = cur[(long)n * 64 + lane];
        float mu = wave_sum(v) * (1.f / 64.f);
        float d = v - mu;
        float var = wave_sum(d * d) * (1.f / 64.f);
        acc += fmaxf(d * rsqrtf(var + 1e-5f) * gg + bb, 0.f);
    }
    __shared__ float sh[16][64];
    sh[w][lane] = acc;
    __syncthreads();
    if (w == 0) {
        float tot = 0.f;
#pragma unroll
        for (int k = 0; k < 16; ++k) tot += sh[k][lane];
        out[gi * 64 + lane] = tot / fmaxf((float)(e - s), 1.f);
    }
}

extern "C" void kernel_launch(void* const* d_in, const int* in_sizes, int n_in,
                              void* d_out, int out_size, void* d_ws, size_t ws_size,
                              hipStream_t stream) {
    (void)in_sizes; (void)n_in; (void)out_size; (void)ws_size;
    const int* x         = (const int*)d_in[0];
    const int* edge_attr = (const int*)d_in[1];
    const int* src       = (const int*)d_in[2];
    const int* dst       = src + NE;
    const int* batch     = (const int*)d_in[3];
    const float* atom_emb = (const float*)d_in[4];
    const float* bond_emb = (const float*)d_in[5];
    const float* t        = (const float*)d_in[6];
    const float* W1       = (const float*)d_in[7];
    const float* b1       = (const float*)d_in[8];
    const float* g1       = (const float*)d_in[9];
    const float* bb1      = (const float*)d_in[10];
    const float* W2       = (const float*)d_in[11];
    const float* b2       = (const float*)d_in[12];
    const float* norm_g   = (const float*)d_in[13];
    const float* norm_b   = (const float*)d_in[14];
    float* out = (float*)d_out;

    size_t off = 0;
    auto alloc = [&](size_t bytes) {
        void* p = (char*)d_ws + off;
        off += (bytes + 255) & ~(size_t)255;
        return p;
    };
    int*    count  = (int*)alloc((size_t)NN * 4);
    int*    wofs   = (int*)alloc((size_t)NN * 4);
    int*    rowptr = (int*)alloc((size_t)(NN + 1) * 4);
    int*    bsum   = (int*)alloc(4096);
    int*    csr32  = (int*)alloc((size_t)NE * 4);
    float*  comb   = (float*)alloc(1000 * 64 * 4);
    float*  xn     = (float*)alloc((size_t)NN * 64 * 4);
    float*  hh     = (float*)alloc((size_t)NN * 64 * 4);
    float*  cur    = (float*)alloc((size_t)NN * 64 * 4);
    int*    gstart = (int*)alloc((size_t)(NG + 1) * 4);
    float2* W1p    = (float2*)alloc((size_t)NL * 64 * 64 * 8);
    float2* W2p    = (float2*)alloc((size_t)NL * 64 * 64 * 8);

    hipMemsetAsync(count, 0, (size_t)NN * 4, stream);
    hipMemsetAsync(wofs, 0, (size_t)NN * 4, stream);

    const int EB = (NE + 255) / 256;
    const int SB = (NN + 255) / 256;
    const int WB = (NN * 64 + 255) / 256;

    k_count<<<EB, 256, 0, stream>>>(dst, count);
    k_scan1<<<SB, 256, 0, stream>>>(count, rowptr + 1, bsum, NN);
    k_scan2<<<1, 256, 0, stream>>>(bsum, SB);
    k_scan3<<<SB, 256, 0, stream>>>(rowptr, bsum, NN);
    k_fill<<<EB, 256, 0, stream>>>(src, dst, edge_attr, rowptr, wofs, csr32);
    k_comb<<<(1000 * 64 + 255) / 256, 256, 0, stream>>>(bond_emb, comb);
    k_atom<<<WB, 256, 0, stream>>>(x, atom_emb, xn);
    k_bounds<<<SB, 256, 0, stream>>>(batch, gstart);
    k_packw<<<(NL * 64 * 64 + 255) / 256, 256, 0, stream>>>(W1, W2, W1p, W2p);

    // Ping-pong activation buffers: writer never aliases the gather source.
    // L0: read xn -> write hh ; L1: read hh -> write xn ;
    // L2: read xn -> write hh ; L3: read hh -> write none.
    k_conv<<<WB, 256, 0, stream>>>(xn, rowptr, csr32, comb, t, 0,
                                   W1p, b1, g1, bb1, W2p, b2, cur, 0,
                                   hh, norm_g + 64, norm_b + 64);
    float* bufs[2] = {hh, xn};
    for (int l = 1; l < NL; ++l) {
        float* hin    = bufs[(l + 1) & 1];   // l=1:hh, l=2:xn, l=3:hh
        float* hh_out = (l < NL - 1) ? bufs[l & 1] : nullptr;
        const float* ng  = norm_g + (l + 1 < NL ? (l + 1) * 64 : 0);
        const float* nbp = norm_b + (l + 1 < NL ? (l + 1) * 64 : 0);
        k_conv<<<WB, 256, 0, stream>>>(hin, rowptr, csr32, comb, t, l,
                                       W1p, b1, g1, bb1, W2p, b2, cur, 1,
                                       hh_out, ng, nbp);
    }
    k_pool2<<<NG, 1024, 0, stream>>>(cur, gstart, norm_g, norm_b, out);
}

// Round 9
// 1423.945 us; speedup vs baseline: 1.0001x; 1.0001x over previous
//
#include <hip/hip_runtime.h>
#include <hip/hip_bf16.h>
#include <hip/hip_fp16.h>

#define NN 80000
#define NE 1280000
#define NL 4
#define NG 256

__device__ __forceinline__ float wave_sum(float v) {
    for (int off = 32; off; off >>= 1) v += __shfl_xor(v, off, 64);
    return v;
}

// ---------------- CSR build ----------------
__global__ void k_count(const int* __restrict__ dst, int* __restrict__ cnt) {
    int e = blockIdx.x * 256 + threadIdx.x;
    if (e < NE) atomicAdd(&cnt[dst[e]], 1);
}

__global__ void k_scan1(const int* __restrict__ in, int* __restrict__ out,
                        int* __restrict__ bsum, int n) {
    __shared__ int ws[4];
    int i = blockIdx.x * 256 + threadIdx.x;
    int v = (i < n) ? in[i] : 0;
    int lane = threadIdx.x & 63, w = threadIdx.x >> 6;
    for (int off = 1; off < 64; off <<= 1) {
        int t = __shfl_up(v, off, 64);
        if (lane >= off) v += t;
    }
    if (lane == 63) ws[w] = v;
    __syncthreads();
    if (threadIdx.x == 0) {
        int acc = 0;
        for (int k = 0; k < 4; k++) { int t = ws[k]; ws[k] = acc; acc += t; }
    }
    __syncthreads();
    v += ws[w];
    if (i < n) out[i] = v;
    if (threadIdx.x == 255) bsum[blockIdx.x] = v;
}

__global__ void k_scan2(int* __restrict__ bsum, int nb) {
    __shared__ int ws[4];
    __shared__ int carry;
    if (threadIdx.x == 0) carry = 0;
    __syncthreads();
    for (int base = 0; base < nb; base += 256) {
        int i = base + threadIdx.x;
        int v = (i < nb) ? bsum[i] : 0;
        int lane = threadIdx.x & 63, w = threadIdx.x >> 6;
        for (int off = 1; off < 64; off <<= 1) {
            int t = __shfl_up(v, off, 64);
            if (lane >= off) v += t;
        }
        if (lane == 63) ws[w] = v;
        __syncthreads();
        if (threadIdx.x == 0) {
            int acc = carry;
            for (int k = 0; k < 4; k++) { int t = ws[k]; ws[k] = acc; acc += t; }
            carry = acc;
        }
        __syncthreads();
        v += ws[w];
        if (i < nb) bsum[i] = v;
        __syncthreads();
    }
}

__global__ void k_scan3(int* __restrict__ rowptr, const int* __restrict__ bsum, int n) {
    int i = blockIdx.x * 256 + threadIdx.x;
    if (i < n) {
        int off = (blockIdx.x > 0) ? bsum[blockIdx.x - 1] : 0;
        rowptr[1 + i] += off;
    }
    if (i == 0 && blockIdx.x == 0) rowptr[0] = 0;
}

// pack (src<<10)|combo into one int (src<2^17, combo<1000)
__global__ void k_fill(const int* __restrict__ src, const int* __restrict__ dst,
                       const int* __restrict__ eattr, const int* __restrict__ rowptr,
                       int* __restrict__ wofs, int* __restrict__ csr32) {
    int e = blockIdx.x * 256 + threadIdx.x;
    if (e >= NE) return;
    int d = dst[e];
    int pos = rowptr[d] + atomicAdd(&wofs[d], 1);
    int a0 = eattr[e * 3], a1 = eattr[e * 3 + 1], a2 = eattr[e * 3 + 2];
    csr32[pos] = (src[e] << 10) | (a0 + a1 * 10 + a2 * 100);
}

// ---------------- encoders / weight packing ----------------
__global__ void k_comb(const float* __restrict__ bond_emb, __half* __restrict__ comb) {
    int wid = (blockIdx.x * 256 + threadIdx.x) >> 6;
    int lane = threadIdx.x & 63;
    if (wid >= 1000) return;
    int a0 = wid % 10, a1 = (wid / 10) % 10, a2 = wid / 100;
    comb[wid * 64 + lane] = __float2half(bond_emb[a0 * 64 + lane] +
                                         bond_emb[(10 + a1) * 64 + lane] +
                                         bond_emb[(20 + a2) * 64 + lane]);
}

__global__ void k_atom(const int* __restrict__ x, const float* __restrict__ atom_emb,
                       __half* __restrict__ xn) {
    int wid = (blockIdx.x * 256 + threadIdx.x) >> 6;
    int lane = threadIdx.x & 63;
    if (wid >= NN) return;
    float acc = 0.f;
#pragma unroll
    for (int f = 0; f < 9; f++) {
        int idx = x[wid * 9 + f] + f * 100;
        acc += atom_emb[idx * 64 + lane];
    }
    xn[wid * 64 + lane] = __float2half(acc);
}

// W1p[l][k][lane] = {W1[l][k][lane], W1[l][k][64+lane]}
// W2p[l][j][lane] = {W2[l][j][lane], W2[l][64+j][lane]}
__global__ void k_packw(const float* __restrict__ W1, const float* __restrict__ W2,
                        float2* __restrict__ W1p, float2* __restrict__ W2p) {
    int i = blockIdx.x * 256 + threadIdx.x;
    if (i >= NL * 64 * 64) return;
    int lane = i & 63, k = (i >> 6) & 63, l = i >> 12;
    W1p[i] = make_float2(W1[(l * 64 + k) * 128 + lane],
                         W1[(l * 64 + k) * 128 + 64 + lane]);
    W2p[i] = make_float2(W2[(l * 128 + k) * 64 + lane],
                         W2[(l * 128 + 64 + k) * 64 + lane]);
}

// ---------------- fused conv: edge-agg + MLP + residual + next-layer prenorm ----------------
// NOTE: hh_out must NOT alias hin (same-dispatch gather race) — caller ping-pongs buffers.
__global__ __launch_bounds__(256) void k_conv(
    const __half* __restrict__ hin, const int* __restrict__ rowptr,
    const int* __restrict__ csr32, const __half* __restrict__ comb,
    const float* __restrict__ t, int l,
    const float2* __restrict__ W1p, const float* __restrict__ b1,
    const float* __restrict__ g1, const float* __restrict__ bb1,
    const float2* __restrict__ W2p, const float* __restrict__ b2,
    float* __restrict__ cur, int residual,
    __half* __restrict__ hh, const float* __restrict__ ng, const float* __restrict__ nb) {
    int wid = (blockIdx.x * 256 + threadIdx.x) >> 6;
    int lane = threadIdx.x & 63;
    if (wid >= NN) return;
    float tl = t[l];
    long oi = (long)wid * 64 + lane;
    float hroot = __half2float(hin[oi]);
    int rs = rowptr[wid], re = rowptr[wid + 1];

    // ---- branch-free aggregation, 8-wide: fp16 gathers (128B/row), 4 acc pairs ----
    float den0 = 0.f, num0 = 0.f, den1 = 0.f, num1 = 0.f;
    float den2 = 0.f, num2 = 0.f, den3 = 0.f, num3 = 0.f;
    for (int base = rs; base < re; base += 64) {
        int nbt = min(64, re - base);
        int ev = (base + lane < re) ? csr32[base + lane] : 0;
        int q = 0;
        for (; q + 7 < nbt; q += 8) {
            int v0 = __shfl(ev, q, 64),     v1 = __shfl(ev, q + 1, 64);
            int v2 = __shfl(ev, q + 2, 64), v3 = __shfl(ev, q + 3, 64);
            int v4 = __shfl(ev, q + 4, 64), v5 = __shfl(ev, q + 5, 64);
            int v6 = __shfl(ev, q + 6, 64), v7 = __shfl(ev, q + 7, 64);
            float h0 = __half2float(hin[(long)(v0 >> 10) * 64 + lane]);
            float c0 = __half2float(comb[(v0 & 1023) * 64 + lane]);
            float h1 = __half2float(hin[(long)(v1 >> 10) * 64 + lane]);
            float c1 = __half2float(comb[(v1 & 1023) * 64 + lane]);
            float h2 = __half2float(hin[(long)(v2 >> 10) * 64 + lane]);
            float c2 = __half2float(comb[(v2 & 1023) * 64 + lane]);
            float h3 = __half2float(hin[(long)(v3 >> 10) * 64 + lane]);
            float c3 = __half2float(comb[(v3 & 1023) * 64 + lane]);
            float h4 = __half2float(hin[(long)(v4 >> 10) * 64 + lane]);
            float c4 = __half2float(comb[(v4 & 1023) * 64 + lane]);
            float h5 = __half2float(hin[(long)(v5 >> 10) * 64 + lane]);
            float c5 = __half2float(comb[(v5 & 1023) * 64 + lane]);
            float h6 = __half2float(hin[(long)(v6 >> 10) * 64 + lane]);
            float c6 = __half2float(comb[(v6 & 1023) * 64 + lane]);
            float h7 = __half2float(hin[(long)(v7 >> 10) * 64 + lane]);
            float c7 = __half2float(comb[(v7 & 1023) * 64 + lane]);
            float m0 = fmaxf(h0 + c0, 0.f) + 1e-7f;
            float m1 = fmaxf(h1 + c1, 0.f) + 1e-7f;
            float m2 = fmaxf(h2 + c2, 0.f) + 1e-7f;
            float m3 = fmaxf(h3 + c3, 0.f) + 1e-7f;
            float m4 = fmaxf(h4 + c4, 0.f) + 1e-7f;
            float m5 = fmaxf(h5 + c5, 0.f) + 1e-7f;
            float m6 = fmaxf(h6 + c6, 0.f) + 1e-7f;
            float m7 = fmaxf(h7 + c7, 0.f) + 1e-7f;
            float e0 = __expf(m0 * tl), e1 = __expf(m1 * tl);
            float e2 = __expf(m2 * tl), e3 = __expf(m3 * tl);
            float e4 = __expf(m4 * tl), e5 = __expf(m5 * tl);
            float e6 = __expf(m6 * tl), e7 = __expf(m7 * tl);
            den0 += e0; num0 = fmaf(e0, m0, num0);
            den1 += e1; num1 = fmaf(e1, m1, num1);
            den2 += e2; num2 = fmaf(e2, m2, num2);
            den3 += e3; num3 = fmaf(e3, m3, num3);
            den0 += e4; num0 = fmaf(e4, m4, num0);
            den1 += e5; num1 = fmaf(e5, m5, num1);
            den2 += e6; num2 = fmaf(e6, m6, num2);
            den3 += e7; num3 = fmaf(e7, m7, num3);
        }
        for (; q < nbt; ++q) {
            int v0 = __shfl(ev, q, 64);
            float h0 = __half2float(hin[(long)(v0 >> 10) * 64 + lane]);
            float c0 = __half2float(comb[(v0 & 1023) * 64 + lane]);
            float m0 = fmaxf(h0 + c0, 0.f) + 1e-7f;
            float e0 = __expf(m0 * tl);
            den0 += e0; num0 = fmaf(e0, m0, num0);
        }
    }
    float den = (den0 + den1) + (den2 + den3);
    float num = (num0 + num1) + (num2 + num3);
    float o = num / (den + 1e-16f) + hroot;
    float curold = residual ? cur[oi] : 0.f;

    // ---- MLP 64 -> 128 -> LN -> ReLU -> 64 (packed float2 fp32 weights) ----
    const float2* W1l = W1p + l * 4096;
    const float2* W2l = W2p + l * 4096;
    float a0 = b1[l * 128 + lane];
    float a1 = b1[l * 128 + 64 + lane];
#pragma unroll 8
    for (int k = 0; k < 64; ++k) {
        float ok = __shfl(o, k, 64);
        float2 w = W1l[k * 64 + lane];
        a0 = fmaf(ok, w.x, a0);
        a1 = fmaf(ok, w.y, a1);
    }
    float mu = wave_sum(a0 + a1) * (1.f / 128.f);
    float d0 = a0 - mu, d1 = a1 - mu;
    float var = wave_sum(d0 * d0 + d1 * d1) * (1.f / 128.f);
    float r = rsqrtf(var + 1e-5f);
    float m0 = fmaxf(d0 * r * g1[l * 128 + lane] + bb1[l * 128 + lane], 0.f);
    float m1 = fmaxf(d1 * r * g1[l * 128 + 64 + lane] + bb1[l * 128 + 64 + lane], 0.f);
    float acc = b2[l * 64 + lane];
#pragma unroll 8
    for (int j = 0; j < 64; ++j) {
        float v0 = __shfl(m0, j, 64);
        float v1 = __shfl(m1, j, 64);
        float2 w = W2l[j * 64 + lane];
        acc = fmaf(v0, w.x, acc);
        acc = fmaf(v1, w.y, acc);
    }
    float curv = curold + acc;
    cur[oi] = curv;

    // ---- fused next-layer prenorm: hh = relu(LN(curv; ng, nb)) in fp16 ----
    if (hh) {
        float mu2 = wave_sum(curv) * (1.f / 64.f);
        float dd = curv - mu2;
        float var2 = wave_sum(dd * dd) * (1.f / 64.f);
        hh[oi] = __float2half(fmaxf(dd * rsqrtf(var2 + 1e-5f) * ng[lane] + nb[lane], 0.f));
    }
}

// ---------------- pooling (atomic-free, batch sorted) ----------------
__global__ void k_bounds(const int* __restrict__ batch, int* __restrict__ gstart) {
    int i = blockIdx.x * 256 + threadIdx.x;
    if (i >= NN) return;
    int b = batch[i];
    if (i == 0) {
        for (int g = 0; g <= b; ++g) gstart[g] = 0;
    } else {
        int pb = batch[i - 1];
        for (int g = pb + 1; g <= b; ++g) gstart[g] = i;
    }
    if (i == NN - 1) {
        for (int g = b + 1; g <= NG; ++g) gstart[g] = NN;
    }
}

__global__ __launch_bounds__(1024) void k_pool2(
    const float* __restrict__ cur, const int* __restrict__ gstart,
    const float* __restrict__ g, const float* __restrict__ b,
    float* __restrict__ out) {
    int gi = blockIdx.x;
    int lane = threadIdx.x & 63, w = threadIdx.x >> 6;
    int s = gstart[gi], e = gstart[gi + 1];
    float gg = g[lane], bb = b[lane];
    float acc = 0.f;
    for (int n = s + w; n < e; n += 16) {
        float v = cur[(long)n * 64 + lane];
        float mu = wave_sum(v) * (1.f / 64.f);
        float d = v - mu;
        float var = wave_sum(d * d) * (1.f / 64.f);
        acc += fmaxf(d * rsqrtf(var + 1e-5f) * gg + bb, 0.f);
    }
    __shared__ float sh[16][64];
    sh[w][lane] = acc;
    __syncthreads();
    if (w == 0) {
        float tot = 0.f;
#pragma unroll
        for (int k = 0; k < 16; ++k) tot += sh[k][lane];
        out[gi * 64 + lane] = tot / fmaxf((float)(e - s), 1.f);
    }
}

extern "C" void kernel_launch(void* const* d_in, const int* in_sizes, int n_in,
                              void* d_out, int out_size, void* d_ws, size_t ws_size,
                              hipStream_t stream) {
    (void)in_sizes; (void)n_in; (void)out_size; (void)ws_size;
    const int* x         = (const int*)d_in[0];
    const int* edge_attr = (const int*)d_in[1];
    const int* src       = (const int*)d_in[2];
    const int* dst       = src + NE;
    const int* batch     = (const int*)d_in[3];
    const float* atom_emb = (const float*)d_in[4];
    const float* bond_emb = (const float*)d_in[5];
    const float* t        = (const float*)d_in[6];
    const float* W1       = (const float*)d_in[7];
    const float* b1       = (const float*)d_in[8];
    const float* g1       = (const float*)d_in[9];
    const float* bb1      = (const float*)d_in[10];
    const float* W2       = (const float*)d_in[11];
    const float* b2       = (const float*)d_in[12];
    const float* norm_g   = (const float*)d_in[13];
    const float* norm_b   = (const float*)d_in[14];
    float* out = (float*)d_out;

    size_t off = 0;
    auto alloc = [&](size_t bytes) {
        void* p = (char*)d_ws + off;
        off += (bytes + 255) & ~(size_t)255;
        return p;
    };
    int*    count  = (int*)alloc((size_t)NN * 4);
    int*    wofs   = (int*)alloc((size_t)NN * 4);
    int*    rowptr = (int*)alloc((size_t)(NN + 1) * 4);
    int*    bsum   = (int*)alloc(4096);
    int*    csr32  = (int*)alloc((size_t)NE * 4);
    __half* comb   = (__half*)alloc(1000 * 64 * 2);
    __half* xnH    = (__half*)alloc((size_t)NN * 64 * 2);
    __half* hhH    = (__half*)alloc((size_t)NN * 64 * 2);
    float*  cur    = (float*)alloc((size_t)NN * 64 * 4);
    int*    gstart = (int*)alloc((size_t)(NG + 1) * 4);
    float2* W1p    = (float2*)alloc((size_t)NL * 64 * 64 * 8);
    float2* W2p    = (float2*)alloc((size_t)NL * 64 * 64 * 8);

    hipMemsetAsync(count, 0, (size_t)NN * 4, stream);
    hipMemsetAsync(wofs, 0, (size_t)NN * 4, stream);

    const int EB = (NE + 255) / 256;
    const int SB = (NN + 255) / 256;
    const int WB = (NN * 64 + 255) / 256;

    k_count<<<EB, 256, 0, stream>>>(dst, count);
    k_scan1<<<SB, 256, 0, stream>>>(count, rowptr + 1, bsum, NN);
    k_scan2<<<1, 256, 0, stream>>>(bsum, SB);
    k_scan3<<<SB, 256, 0, stream>>>(rowptr, bsum, NN);
    k_fill<<<EB, 256, 0, stream>>>(src, dst, edge_attr, rowptr, wofs, csr32);
    k_comb<<<(1000 * 64 + 255) / 256, 256, 0, stream>>>(bond_emb, comb);
    k_atom<<<WB, 256, 0, stream>>>(x, atom_emb, xnH);
    k_bounds<<<SB, 256, 0, stream>>>(batch, gstart);
    k_packw<<<(NL * 64 * 64 + 255) / 256, 256, 0, stream>>>(W1, W2, W1p, W2p);

    // Ping-pong activation buffers: writer never aliases the gather source.
    // L0: read xnH -> write hhH ; L1: read hhH -> write xnH ;
    // L2: read xnH -> write hhH ; L3: read hhH -> write none.
    k_conv<<<WB, 256, 0, stream>>>(xnH, rowptr, csr32, comb, t, 0,
                                   W1p, b1, g1, bb1, W2p, b2, cur, 0,
                                   hhH, norm_g + 64, norm_b + 64);
    __half* bufs[2] = {hhH, xnH};
    for (int l = 1; l < NL; ++l) {
        __half* hin    = bufs[(l + 1) & 1];   // l=1:hhH, l=2:xnH, l=3:hhH
        __half* hh_out = (l < NL - 1) ? bufs[l & 1] : nullptr;
        const float* ng  = norm_g + (l + 1 < NL ? (l + 1) * 64 : 0);
        const float* nbp = norm_b + (l + 1 < NL ? (l + 1) * 64 : 0);
        k_conv<<<WB, 256, 0, stream>>>(hin, rowptr, csr32, comb, t, l,
                                       W1p, b1, g1, bb1, W2p, b2, cur, 1,
                                       hh_out, ng, nbp);
    }
    k_pool2<<<NG, 1024, 0, stream>>>(cur, gstart, norm_g, norm_b, out);
}

// Round 10
// 1264.103 us; speedup vs baseline: 1.1266x; 1.1264x over previous
//
#include <hip/hip_runtime.h>
#include <hip/hip_bf16.h>
#include <hip/hip_fp16.h>

#define NN 80000
#define NE 1280000
#define NL 4
#define NG 256

__device__ __forceinline__ float wave_sum(float v) {
    for (int off = 32; off; off >>= 1) v += __shfl_xor(v, off, 64);
    return v;
}

// ---------------- CSR build ----------------
__global__ void k_count(const int* __restrict__ dst, int* __restrict__ cnt) {
    int e = blockIdx.x * 256 + threadIdx.x;
    if (e < NE) atomicAdd(&cnt[dst[e]], 1);
}

__global__ void k_scan1(const int* __restrict__ in, int* __restrict__ out,
                        int* __restrict__ bsum, int n) {
    __shared__ int ws[4];
    int i = blockIdx.x * 256 + threadIdx.x;
    int v = (i < n) ? in[i] : 0;
    int lane = threadIdx.x & 63, w = threadIdx.x >> 6;
    for (int off = 1; off < 64; off <<= 1) {
        int t = __shfl_up(v, off, 64);
        if (lane >= off) v += t;
    }
    if (lane == 63) ws[w] = v;
    __syncthreads();
    if (threadIdx.x == 0) {
        int acc = 0;
        for (int k = 0; k < 4; k++) { int t = ws[k]; ws[k] = acc; acc += t; }
    }
    __syncthreads();
    v += ws[w];
    if (i < n) out[i] = v;
    if (threadIdx.x == 255) bsum[blockIdx.x] = v;
}

__global__ void k_scan2(int* __restrict__ bsum, int nb) {
    __shared__ int ws[4];
    __shared__ int carry;
    if (threadIdx.x == 0) carry = 0;
    __syncthreads();
    for (int base = 0; base < nb; base += 256) {
        int i = base + threadIdx.x;
        int v = (i < nb) ? bsum[i] : 0;
        int lane = threadIdx.x & 63, w = threadIdx.x >> 6;
        for (int off = 1; off < 64; off <<= 1) {
            int t = __shfl_up(v, off, 64);
            if (lane >= off) v += t;
        }
        if (lane == 63) ws[w] = v;
        __syncthreads();
        if (threadIdx.x == 0) {
            int acc = carry;
            for (int k = 0; k < 4; k++) { int t = ws[k]; ws[k] = acc; acc += t; }
            carry = acc;
        }
        __syncthreads();
        v += ws[w];
        if (i < nb) bsum[i] = v;
        __syncthreads();
    }
}

__global__ void k_scan3(int* __restrict__ rowptr, const int* __restrict__ bsum, int n) {
    int i = blockIdx.x * 256 + threadIdx.x;
    if (i < n) {
        int off = (blockIdx.x > 0) ? bsum[blockIdx.x - 1] : 0;
        rowptr[1 + i] += off;
    }
    if (i == 0 && blockIdx.x == 0) rowptr[0] = 0;
}

// pack (src<<10)|combo into one int (src<2^17, combo<1000)
__global__ void k_fill(const int* __restrict__ src, const int* __restrict__ dst,
                       const int* __restrict__ eattr, const int* __restrict__ rowptr,
                       int* __restrict__ wofs, int* __restrict__ csr32) {
    int e = blockIdx.x * 256 + threadIdx.x;
    if (e >= NE) return;
    int d = dst[e];
    int pos = rowptr[d] + atomicAdd(&wofs[d], 1);
    int a0 = eattr[e * 3], a1 = eattr[e * 3 + 1], a2 = eattr[e * 3 + 2];
    csr32[pos] = (src[e] << 10) | (a0 + a1 * 10 + a2 * 100);
}

// ---------------- encoders / weight packing ----------------
__global__ void k_comb(const float* __restrict__ bond_emb, __half* __restrict__ comb) {
    int wid = (blockIdx.x * 256 + threadIdx.x) >> 6;
    int lane = threadIdx.x & 63;
    if (wid >= 1000) return;
    int a0 = wid % 10, a1 = (wid / 10) % 10, a2 = wid / 100;
    comb[wid * 64 + lane] = __float2half(bond_emb[a0 * 64 + lane] +
                                         bond_emb[(10 + a1) * 64 + lane] +
                                         bond_emb[(20 + a2) * 64 + lane]);
}

__global__ void k_atom(const int* __restrict__ x, const float* __restrict__ atom_emb,
                       __half* __restrict__ xn) {
    int wid = (blockIdx.x * 256 + threadIdx.x) >> 6;
    int lane = threadIdx.x & 63;
    if (wid >= NN) return;
    float acc = 0.f;
#pragma unroll
    for (int f = 0; f < 9; f++) {
        int idx = x[wid * 9 + f] + f * 100;
        acc += atom_emb[idx * 64 + lane];
    }
    xn[wid * 64 + lane] = __float2half(acc);
}

// W1p[l][k][lane] = {W1[l][k][lane], W1[l][k][64+lane]}
// W2p[l][j][lane] = {W2[l][j][lane], W2[l][64+j][lane]}
__global__ void k_packw(const float* __restrict__ W1, const float* __restrict__ W2,
                        float2* __restrict__ W1p, float2* __restrict__ W2p) {
    int i = blockIdx.x * 256 + threadIdx.x;
    if (i >= NL * 64 * 64) return;
    int lane = i & 63, k = (i >> 6) & 63, l = i >> 12;
    W1p[i] = make_float2(W1[(l * 64 + k) * 128 + lane],
                         W1[(l * 64 + k) * 128 + 64 + lane]);
    W2p[i] = make_float2(W2[(l * 128 + k) * 64 + lane],
                         W2[(l * 128 + 64 + k) * 64 + lane]);
}

// ---------------- fused conv: edge-agg + LDS-weight MLP + residual + next-layer prenorm ----
// 1024 threads = 16 waves = 16 nodes per block; W1+W2 staged in 64KB LDS.
// NOTE: hh_out must NOT alias hin (same-dispatch gather race) — caller ping-pongs buffers.
__global__ __launch_bounds__(1024) void k_conv(
    const __half* __restrict__ hin, const int* __restrict__ rowptr,
    const int* __restrict__ csr32, const __half* __restrict__ comb,
    const float* __restrict__ t, int l,
    const float2* __restrict__ W1p, const float* __restrict__ b1,
    const float* __restrict__ g1, const float* __restrict__ bb1,
    const float2* __restrict__ W2p, const float* __restrict__ b2,
    float* __restrict__ cur, int residual,
    __half* __restrict__ hh, const float* __restrict__ ng, const float* __restrict__ nb) {
    __shared__ float2 sW[8192];          // sW1 = sW[0..4095], sW2 = sW[4096..8191]
    {
        const float2* W1l = W1p + l * 4096;
        const float2* W2l = W2p + l * 4096;
        for (int i = threadIdx.x; i < 4096; i += 1024) {
            sW[i] = W1l[i];
            sW[4096 + i] = W2l[i];
        }
    }
    __syncthreads();

    int wid = blockIdx.x * 16 + (threadIdx.x >> 6);   // NN == 5000*16 exactly
    int lane = threadIdx.x & 63;
    float tl = t[l];
    long oi = (long)wid * 64 + lane;
    float hroot = __half2float(hin[oi]);
    int rs = rowptr[wid], re = rowptr[wid + 1];

    // ---- branch-free aggregation: simple per-edge uniform csr load, compiler-pipelined ----
    float den = 0.f, num = 0.f;
#pragma unroll 4
    for (int p = rs; p < re; ++p) {
        int v = csr32[p];
        float h = __half2float(hin[(long)(v >> 10) * 64 + lane]);
        float c = __half2float(comb[(v & 1023) * 64 + lane]);
        float m = fmaxf(h + c, 0.f) + 1e-7f;
        float e = __expf(m * tl);
        den += e;
        num = fmaf(e, m, num);
    }
    float o = num / (den + 1e-16f) + hroot;
    float curold = residual ? cur[oi] : 0.f;

    // ---- MLP 64 -> 128 -> LN -> ReLU -> 64 (weights from LDS) ----
    float a0 = b1[l * 128 + lane];
    float a1 = b1[l * 128 + 64 + lane];
#pragma unroll 8
    for (int k = 0; k < 64; ++k) {
        float ok = __shfl(o, k, 64);
        float2 w = sW[k * 64 + lane];
        a0 = fmaf(ok, w.x, a0);
        a1 = fmaf(ok, w.y, a1);
    }
    float mu = wave_sum(a0 + a1) * (1.f / 128.f);
    float d0 = a0 - mu, d1 = a1 - mu;
    float var = wave_sum(d0 * d0 + d1 * d1) * (1.f / 128.f);
    float r = rsqrtf(var + 1e-5f);
    float m0 = fmaxf(d0 * r * g1[l * 128 + lane] + bb1[l * 128 + lane], 0.f);
    float m1 = fmaxf(d1 * r * g1[l * 128 + 64 + lane] + bb1[l * 128 + 64 + lane], 0.f);
    float acc = b2[l * 64 + lane];
#pragma unroll 8
    for (int j = 0; j < 64; ++j) {
        float v0 = __shfl(m0, j, 64);
        float v1 = __shfl(m1, j, 64);
        float2 w = sW[4096 + j * 64 + lane];
        acc = fmaf(v0, w.x, acc);
        acc = fmaf(v1, w.y, acc);
    }
    float curv = curold + acc;
    cur[oi] = curv;

    // ---- fused next-layer prenorm: hh = relu(LN(curv; ng, nb)) in fp16 ----
    if (hh) {
        float mu2 = wave_sum(curv) * (1.f / 64.f);
        float dd = curv - mu2;
        float var2 = wave_sum(dd * dd) * (1.f / 64.f);
        hh[oi] = __float2half(fmaxf(dd * rsqrtf(var2 + 1e-5f) * ng[lane] + nb[lane], 0.f));
    }
}

// ---------------- pooling (atomic-free, batch sorted) ----------------
__global__ void k_bounds(const int* __restrict__ batch, int* __restrict__ gstart) {
    int i = blockIdx.x * 256 + threadIdx.x;
    if (i >= NN) return;
    int b = batch[i];
    if (i == 0) {
        for (int g = 0; g <= b; ++g) gstart[g] = 0;
    } else {
        int pb = batch[i - 1];
        for (int g = pb + 1; g <= b; ++g) gstart[g] = i;
    }
    if (i == NN - 1) {
        for (int g = b + 1; g <= NG; ++g) gstart[g] = NN;
    }
}

__global__ __launch_bounds__(1024) void k_pool2(
    const float* __restrict__ cur, const int* __restrict__ gstart,
    const float* __restrict__ g, const float* __restrict__ b,
    float* __restrict__ out) {
    int gi = blockIdx.x;
    int lane = threadIdx.x & 63, w = threadIdx.x >> 6;
    int s = gstart[gi], e = gstart[gi + 1];
    float gg = g[lane], bb = b[lane];
    float acc = 0.f;
    for (int n = s + w; n < e; n += 16) {
        float v = cur[(long)n * 64 + lane];
        float mu = wave_sum(v) * (1.f / 64.f);
        float d = v - mu;
        float var = wave_sum(d * d) * (1.f / 64.f);
        acc += fmaxf(d * rsqrtf(var + 1e-5f) * gg + bb, 0.f);
    }
    __shared__ float sh[16][64];
    sh[w][lane] = acc;
    __syncthreads();
    if (w == 0) {
        float tot = 0.f;
#pragma unroll
        for (int k = 0; k < 16; ++k) tot += sh[k][lane];
        out[gi * 64 + lane] = tot / fmaxf((float)(e - s), 1.f);
    }
}

extern "C" void kernel_launch(void* const* d_in, const int* in_sizes, int n_in,
                              void* d_out, int out_size, void* d_ws, size_t ws_size,
                              hipStream_t stream) {
    (void)in_sizes; (void)n_in; (void)out_size; (void)ws_size;
    const int* x         = (const int*)d_in[0];
    const int* edge_attr = (const int*)d_in[1];
    const int* src       = (const int*)d_in[2];
    const int* dst       = src + NE;
    const int* batch     = (const int*)d_in[3];
    const float* atom_emb = (const float*)d_in[4];
    const float* bond_emb = (const float*)d_in[5];
    const float* t        = (const float*)d_in[6];
    const float* W1       = (const float*)d_in[7];
    const float* b1       = (const float*)d_in[8];
    const float* g1       = (const float*)d_in[9];
    const float* bb1      = (const float*)d_in[10];
    const float* W2       = (const float*)d_in[11];
    const float* b2       = (const float*)d_in[12];
    const float* norm_g   = (const float*)d_in[13];
    const float* norm_b   = (const float*)d_in[14];
    float* out = (float*)d_out;

    size_t off = 0;
    auto alloc = [&](size_t bytes) {
        void* p = (char*)d_ws + off;
        off += (bytes + 255) & ~(size_t)255;
        return p;
    };
    int*    count  = (int*)alloc((size_t)NN * 4);
    int*    wofs   = (int*)alloc((size_t)NN * 4);
    int*    rowptr = (int*)alloc((size_t)(NN + 1) * 4);
    int*    bsum   = (int*)alloc(4096);
    int*    csr32  = (int*)alloc((size_t)NE * 4);
    __half* comb   = (__half*)alloc(1000 * 64 * 2);
    __half* xnH    = (__half*)alloc((size_t)NN * 64 * 2);
    __half* hhH    = (__half*)alloc((size_t)NN * 64 * 2);
    float*  cur    = (float*)alloc((size_t)NN * 64 * 4);
    int*    gstart = (int*)alloc((size_t)(NG + 1) * 4);
    float2* W1p    = (float2*)alloc((size_t)NL * 64 * 64 * 8);
    float2* W2p    = (float2*)alloc((size_t)NL * 64 * 64 * 8);

    hipMemsetAsync(count, 0, (size_t)NN * 4, stream);
    hipMemsetAsync(wofs, 0, (size_t)NN * 4, stream);

    const int EB = (NE + 255) / 256;
    const int SB = (NN + 255) / 256;
    const int WB = (NN * 64 + 255) / 256;

    k_count<<<EB, 256, 0, stream>>>(dst, count);
    k_scan1<<<SB, 256, 0, stream>>>(count, rowptr + 1, bsum, NN);
    k_scan2<<<1, 256, 0, stream>>>(bsum, SB);
    k_scan3<<<SB, 256, 0, stream>>>(rowptr, bsum, NN);
    k_fill<<<EB, 256, 0, stream>>>(src, dst, edge_attr, rowptr, wofs, csr32);
    k_comb<<<(1000 * 64 + 255) / 256, 256, 0, stream>>>(bond_emb, comb);
    k_atom<<<WB, 256, 0, stream>>>(x, atom_emb, xnH);
    k_bounds<<<SB, 256, 0, stream>>>(batch, gstart);
    k_packw<<<(NL * 64 * 64 + 255) / 256, 256, 0, stream>>>(W1, W2, W1p, W2p);

    // Ping-pong activation buffers: writer never aliases the gather source.
    // L0: read xnH -> write hhH ; L1: read hhH -> write xnH ;
    // L2: read xnH -> write hhH ; L3: read hhH -> write none.
    const int CB = NN / 16;   // 5000 blocks, 16 nodes (waves) each
    k_conv<<<CB, 1024, 0, stream>>>(xnH, rowptr, csr32, comb, t, 0,
                                    W1p, b1, g1, bb1, W2p, b2, cur, 0,
                                    hhH, norm_g + 64, norm_b + 64);
    __half* bufs[2] = {hhH, xnH};
    for (int l = 1; l < NL; ++l) {
        __half* hin    = bufs[(l + 1) & 1];   // l=1:hhH, l=2:xnH, l=3:hhH
        __half* hh_out = (l < NL - 1) ? bufs[l & 1] : nullptr;
        const float* ng  = norm_g + (l + 1 < NL ? (l + 1) * 64 : 0);
        const float* nbp = norm_b + (l + 1 < NL ? (l + 1) * 64 : 0);
        k_conv<<<CB, 1024, 0, stream>>>(hin, rowptr, csr32, comb, t, l,
                                        W1p, b1, g1, bb1, W2p, b2, cur, 1,
                                        hh_out, ng, nbp);
    }
    k_pool2<<<NG, 1024, 0, stream>>>(cur, gstart, norm_g, norm_b, out);
}